// Round 9
// baseline (497.179 us; speedup 1.0000x reference)
//
#include <hip/hip_runtime.h>
#include <hip/hip_bf16.h>
#include <cstdint>
#include <cstddef>

#define S_ 256
#define N_ 1024
#define H_ 512
#define AD_ 128
static constexpr int M_TOTAL = N_ * S_;   // 262144 rows per stream (m = s*N + n)

typedef __attribute__((ext_vector_type(8))) short short8;
typedef __attribute__((ext_vector_type(4))) float f32x4;

typedef const __attribute__((address_space(1))) unsigned int* gas_ptr;
typedef __attribute__((address_space(3))) unsigned int* las_ptr;

// pack 8 f32 -> 8 bf16 (RNE)
__device__ __forceinline__ short8 pack8(float4 a, float4 b) {
  union { short8 s; __hip_bfloat162 h[4]; } u;
  u.h[0] = __float22bfloat162_rn(make_float2(a.x, a.y));
  u.h[1] = __float22bfloat162_rn(make_float2(a.z, a.w));
  u.h[2] = __float22bfloat162_rn(make_float2(b.x, b.y));
  u.h[3] = __float22bfloat162_rn(make_float2(b.z, b.w));
  return u.s;
}

// ---------------------------------------------------------------------------
// K0: W1 [H][AD] f32 -> MFMA-fragment-ordered bf16 (B-frag = linear 16B/lane).
// ---------------------------------------------------------------------------
__global__ __launch_bounds__(256) void k_w1frag(
    const float* __restrict__ w1_pre, const float* __restrict__ w1_fol,
    unsigned short* __restrict__ w1f) {
  int idx = blockIdx.x * 256 + threadIdx.x;  // 0..65535
  int st = blockIdx.y;
  const float* w1 = st ? w1_fol : w1_pre;
  int j = idx & 7;
  int lane = (idx >> 3) & 63;
  int c = (idx >> 9) & 7;
  int kk = idx >> 12;
  int k = kk * 32 + ((lane >> 4) << 3) + j;
  int d = c * 16 + (lane & 15);
  __hip_bfloat16 hb = __float2bfloat16(w1[(size_t)k * AD_ + d]);
  w1f[(size_t)st * 65536 + idx] = *(unsigned short*)&hb;
}

// ---------------------------------------------------------------------------
// K1: inclusive prefix sum of is_valid -> pos (rank-1), per stream.
// ---------------------------------------------------------------------------
__global__ __launch_bounds__(1024) void k_scan(
    const int* __restrict__ valid_pre, const int* __restrict__ valid_fol,
    int* __restrict__ pos) {
  const int st = blockIdx.x;
  const int* valid = st ? valid_fol : valid_pre;
  __shared__ int buf[1024];
  const int t = threadIdx.x;
  buf[t] = valid[t];
  __syncthreads();
  for (int off = 1; off < 1024; off <<= 1) {
    int v = (t >= off) ? buf[t - off] : 0;
    __syncthreads();
    buf[t] += v;
    __syncthreads();
  }
  pos[st * N_ + t] = buf[t] - 1;
}

// ---------------------------------------------------------------------------
// K2: logits GEMM. A staged via global_load_lds (wave-linear 1KB bursts, the
// fragment permutation + bank-XOR folded into the per-lane GLOBAL source
// address; ds_read applies the same XOR). 512 thr = 8 waves x 16 rows = 128
// rows/block; K in 16 chunks of 32 floats, A dbuf (32 KB LDS -> 2 blocks/CU).
// B single-buffered in regs, reloaded after last use each chunk.
// ---------------------------------------------------------------------------
__global__ __launch_bounds__(512) void k_logits(
    const float* __restrict__ emb_pre, const float* __restrict__ emb_fol,
    const unsigned short* __restrict__ w1f,
    const float* __restrict__ w2_pre, const float* __restrict__ w2_fol,
    float* __restrict__ logits) {
  __shared__ __align__(16) float As[2][128][32];   // 32 KB, 16B-group swizzled

  const int bid = blockIdx.x;
  const int st = bid >> 11;                  // 2048 blocks per stream
  const int m0 = (bid & 2047) * 128;
  const float* __restrict__ emb = st ? emb_fol : emb_pre;
  const float* __restrict__ w2  = st ? w2_fol : w2_pre;

  const int t = threadIdx.x;
  const int w = t >> 6, lane = t & 63;
  const int r16 = lane & 15, kq = lane >> 4;
  const unsigned short* __restrict__ bb = w1f + (size_t)st * 65536 + (size_t)lane * 8;

  // staging: instr j covers rows [w*16+j*8, +8); lane -> row +(lane>>3),
  // LDS slot g'=lane&7; source col-group = g' ^ (row&7)  (inverse swizzle)
  const int rl0 = w * 16 + (lane >> 3);
  const int rl1 = rl0 + 8;
  const float* src0 = emb + (size_t)(m0 + rl0) * H_ + (((lane & 7) ^ (rl0 & 7)) << 2);
  const float* src1 = emb + (size_t)(m0 + rl1) * H_ + (((lane & 7) ^ (rl1 & 7)) << 2);

  f32x4 acc[8];
#pragma unroll
  for (int cc = 0; cc < 8; ++cc) acc[cc] = (f32x4){0.f, 0.f, 0.f, 0.f};
  short8 B[8];

  // prologue: stage chunk 0 + load B chunk 0
  __builtin_amdgcn_global_load_lds((gas_ptr)src0, (las_ptr)&As[0][w * 16][0], 16, 0, 0);
  __builtin_amdgcn_global_load_lds((gas_ptr)src1, (las_ptr)&As[0][w * 16 + 8][0], 16, 0, 0);
#pragma unroll
  for (int cc = 0; cc < 8; ++cc) B[cc] = *(const short8*)(bb + cc * 512);
  __syncthreads();

  // fragment read offsets (swizzled)
  const int row = w * 16 + r16;
  const int sw = r16 & 7;
  const int sl0 = ((kq * 2) ^ sw) * 4;
  const int sl1 = ((kq * 2 + 1) ^ sw) * 4;

#pragma unroll
  for (int kk = 0; kk < 16; ++kk) {
    const int b = kk & 1;
    if (kk < 15) {  // stage next chunk into the other buffer
      __builtin_amdgcn_global_load_lds((gas_ptr)(src0 + (kk + 1) * 32),
                                       (las_ptr)&As[b ^ 1][w * 16][0], 16, 0, 0);
      __builtin_amdgcn_global_load_lds((gas_ptr)(src1 + (kk + 1) * 32),
                                       (las_ptr)&As[b ^ 1][w * 16 + 8][0], 16, 0, 0);
    }
    float4 x0 = *(const float4*)&As[b][row][sl0];
    float4 x1 = *(const float4*)&As[b][row][sl1];
    short8 a = pack8(x0, x1);
#pragma unroll
    for (int cc = 0; cc < 8; ++cc)
      acc[cc] = __builtin_amdgcn_mfma_f32_16x16x32_bf16(a, B[cc], acc[cc], 0, 0, 0);
    if (kk < 15) {  // reload B for next chunk (after last use this chunk)
#pragma unroll
      for (int cc = 0; cc < 8; ++cc)
        B[cc] = *(const short8*)(bb + (kk + 1) * 4096 + cc * 512);
    }
    __syncthreads();  // drains vmcnt (stage + B) and fences dbuf swap
  }

  // epilogue: tanh (exp-form), @W2, 16-lane reduce, write logits
  float w2v0[8], w2v1[8];
#pragma unroll
  for (int cc = 0; cc < 8; ++cc) {
    w2v0[cc] = w2[(cc * 16 + r16) * 2 + 0];
    w2v1[cc] = w2[(cc * 16 + r16) * 2 + 1];
  }
#pragma unroll
  for (int q = 0; q < 4; ++q) {
    float p0 = 0.f, p1 = 0.f;
#pragma unroll
    for (int cc = 0; cc < 8; ++cc) {
      float xc = fminf(fmaxf(acc[cc][q], -10.f), 10.f);
      float e  = __expf(2.f * xc);
      float th = (e - 1.f) / (e + 1.f);
      p0 += th * w2v0[cc];
      p1 += th * w2v1[cc];
    }
    p0 += __shfl_xor(p0, 1); p0 += __shfl_xor(p0, 2);
    p0 += __shfl_xor(p0, 4); p0 += __shfl_xor(p0, 8);
    p1 += __shfl_xor(p1, 1); p1 += __shfl_xor(p1, 2);
    p1 += __shfl_xor(p1, 4); p1 += __shfl_xor(p1, 8);
    if (r16 == 0) {
      int m = m0 + w * 16 + kq * 4 + q;
      logits[((size_t)st * M_TOTAL + m) * 2 + 0] = p0;
      logits[((size_t)st * M_TOTAL + m) * 2 + 1] = p1;
    }
  }
}

// ---------------------------------------------------------------------------
// K3: per (stream, n): double softmax over s (source space), fold r-mean.
// logits layout [st][s][n][2]; wbar [st][n][s].
// ---------------------------------------------------------------------------
template <bool MAXRED>
__device__ __forceinline__ float blockRed(float v, float* buf) {
#pragma unroll
  for (int off = 32; off; off >>= 1) {
    float o = __shfl_xor(v, off);
    v = MAXRED ? fmaxf(v, o) : (v + o);
  }
  __syncthreads();
  if ((threadIdx.x & 63) == 0) buf[threadIdx.x >> 6] = v;
  __syncthreads();
  float r = buf[0];
#pragma unroll
  for (int i = 1; i < 4; ++i) r = MAXRED ? fmaxf(r, buf[i]) : (r + buf[i]);
  return r;
}

__global__ __launch_bounds__(256) void k_softmax(
    const float* __restrict__ logits,
    const unsigned char* __restrict__ mask_pre, const unsigned char* __restrict__ mask_fol,
    float* __restrict__ wbar) {
  const int n  = blockIdx.x;
  const int st = blockIdx.y;
  const unsigned char* mask = st ? mask_fol : mask_pre;
  const int s = threadIdx.x;

  float2 l = *(const float2*)&logits[((size_t)st * M_TOTAL + (size_t)s * N_ + n) * 2];
  const bool mk = mask[(size_t)n * S_ + s] != 0;

  __shared__ float buf[4];
  float q[2];
  float lv[2] = {l.x, l.y};
#pragma unroll
  for (int r = 0; r < 2; ++r) {
    float m1 = blockRed<true>(lv[r], buf);
    float e1 = __expf(lv[r] - m1);
    float s1 = blockRed<false>(e1, buf);
    float p1 = e1 / s1;                       // first softmax (unmasked)
    float v  = mk ? -INFINITY : p1;           // mask the probabilities
    float m2 = blockRed<true>(v, buf);
    float e2 = mk ? 0.f : __expf(v - m2);
    float s2 = blockRed<false>(e2, buf);
    q[r] = e2 / s2;                           // second softmax
  }
  wbar[((size_t)st * N_ + n) * S_ + s] = 0.5f * (q[0] + q[1]);
}

// ---------------------------------------------------------------------------
// K4: PV in memory order. Block = (st, n-chunk of 16, s-half). Per s-step one
// 32 KB contiguous burst (16 adjacent n-rows x full H). part[st][sh][n][h].
// ---------------------------------------------------------------------------
__global__ __launch_bounds__(512) void k_pv2(
    const float* __restrict__ emb_pre, const float* __restrict__ emb_fol,
    const float* __restrict__ wbar,
    float* __restrict__ part) {
  const int bid = blockIdx.x;          // 0..255
  const int st  = bid >> 7;
  const int idx = bid & 127;
  const int nc  = idx >> 1;            // 0..63
  const int sh  = idx & 1;             // 0..1
  const int n0 = nc * 16, s0 = sh * 128;
  const float* __restrict__ emb = st ? emb_fol : emb_pre;

  const int t = threadIdx.x;
  const int nl = t >> 5;               // 0..15 (n-row within chunk)
  const int c0 = (t & 31) * 4;         // h-base; acc j covers c0 + j*128

  __shared__ float wl[16][128];
  for (int i = t; i < 2048; i += 512) {
    int j = i >> 7, sl = i & 127;
    wl[j][sl] = wbar[((size_t)st * N_ + n0 + j) * S_ + s0 + sl];
  }
  __syncthreads();

  float4 acc[4], cur[4], nxt[4];
#pragma unroll
  for (int j = 0; j < 4; ++j) acc[j] = (float4){0.f, 0.f, 0.f, 0.f};

  // s descending (most recently L3-resident rows first)
  const float* rowp = emb + ((size_t)(s0 + 127) * N_ + n0 + nl) * H_ + c0;
  const size_t SSTR = (size_t)N_ * H_;
#pragma unroll
  for (int j = 0; j < 4; ++j) cur[j] = *(const float4*)(rowp + j * 128);

  for (int sl = 127; sl >= 0; --sl) {
    const float* nrow = rowp - SSTR;
    if (sl > 0) {
#pragma unroll
      for (int j = 0; j < 4; ++j) nxt[j] = *(const float4*)(nrow + j * 128);
    }
    const float wv = wl[nl][sl];
#pragma unroll
    for (int j = 0; j < 4; ++j) {
      acc[j].x += wv * cur[j].x;
      acc[j].y += wv * cur[j].y;
      acc[j].z += wv * cur[j].z;
      acc[j].w += wv * cur[j].w;
    }
#pragma unroll
    for (int j = 0; j < 4; ++j) cur[j] = nxt[j];
    rowp = nrow;
  }

  float* pp = part + (((size_t)(st * 2 + sh) * N_) + n0 + nl) * H_ + c0;
#pragma unroll
  for (int j = 0; j < 4; ++j) *(float4*)(pp + j * 128) = acc[j];
}

// ---------------------------------------------------------------------------
// K5: combine s-halves + valid/pos gather -> out[n][st*512 + h].
// ---------------------------------------------------------------------------
__global__ __launch_bounds__(256) void k_combine(
    const float* __restrict__ part, const int* __restrict__ pos,
    const int* __restrict__ valid_pre, const int* __restrict__ valid_fol,
    float* __restrict__ out) {
  const int n = blockIdx.x, t = threadIdx.x;
  const int st = t >> 7;
  const int c = (t & 127) * 4;
  const int* valid = st ? valid_fol : valid_pre;
  float4 r = {0.f, 0.f, 0.f, 0.f};
  if (valid[n] > 0) {
    int np = pos[st * N_ + n]; if (np < 0) np = 0;
    float4 a = *(const float4*)&part[(((size_t)(st * 2 + 0) * N_) + np) * H_ + c];
    float4 b = *(const float4*)&part[(((size_t)(st * 2 + 1) * N_) + np) * H_ + c];
    r.x = a.x + b.x; r.y = a.y + b.y; r.z = a.z + b.z; r.w = a.w + b.w;
  }
  *(float4*)&out[(size_t)n * 1024 + st * 512 + c] = r;
}

// ---------------------------------------------------------------------------
extern "C" void kernel_launch(void* const* d_in, const int* in_sizes, int n_in,
                              void* d_out, int out_size, void* d_ws, size_t ws_size,
                              hipStream_t stream) {
  const float* emb_pre = (const float*)d_in[0];
  const float* emb_fol = (const float*)d_in[1];
  const unsigned char* mask_pre = (const unsigned char*)d_in[2];
  const unsigned char* mask_fol = (const unsigned char*)d_in[3];
  const int* valid_pre = (const int*)d_in[4];
  const int* valid_fol = (const int*)d_in[5];
  const float* w1_pre = (const float*)d_in[6];
  const float* w2_pre = (const float*)d_in[7];
  const float* w1_fol = (const float*)d_in[8];
  const float* w2_fol = (const float*)d_in[9];
  float* out = (float*)d_out;

  char* ws = (char*)d_ws;
  unsigned short* w1f = (unsigned short*)ws;                    // 256 KiB
  int*   pos    = (int*)(ws + 262144);                          // 8 KiB
  float* logits = (float*)(ws + 270336);                        // 4 MiB  [2][S][N][2]
  float* wbar   = (float*)(ws + 270336 + 4194304);              // 2 MiB  [2][N][S]
  float* part   = (float*)(ws + 270336 + 4194304 + 2097152);    // 8 MiB  [2][2][N][H]

  hipLaunchKernelGGL(k_w1frag, dim3(256, 2), dim3(256), 0, stream,
                     w1_pre, w1_fol, w1f);
  hipLaunchKernelGGL(k_scan, dim3(2), dim3(1024), 0, stream,
                     valid_pre, valid_fol, pos);
  hipLaunchKernelGGL(k_logits, dim3(4096), dim3(512), 0, stream,
                     emb_pre, emb_fol, w1f, w2_pre, w2_fol, logits);
  hipLaunchKernelGGL(k_softmax, dim3(N_, 2), dim3(256), 0, stream,
                     logits, mask_pre, mask_fol, wbar);
  hipLaunchKernelGGL(k_pv2, dim3(256), dim3(512), 0, stream,
                     emb_pre, emb_fol, wbar, part);
  hipLaunchKernelGGL(k_combine, dim3(N_), dim3(256), 0, stream,
                     part, pos, valid_pre, valid_fol, out);
}

// Round 10
// 493.963 us; speedup vs baseline: 1.0065x; 1.0065x over previous
//
#include <hip/hip_runtime.h>
#include <hip/hip_bf16.h>
#include <cstdint>
#include <cstddef>

#define S_ 256
#define N_ 1024
#define H_ 512
#define AD_ 128
static constexpr int M_TOTAL = N_ * S_;   // 262144 rows per stream (m = s*N + n)

typedef __attribute__((ext_vector_type(8))) short short8;
typedef __attribute__((ext_vector_type(4))) float f32x4;

// ---------------------------------------------------------------------------
// K0: W1 [H][AD] f32 -> MFMA-fragment-ordered bf16 (B-frag = linear 16B/lane).
// ---------------------------------------------------------------------------
__global__ __launch_bounds__(256) void k_w1frag(
    const float* __restrict__ w1_pre, const float* __restrict__ w1_fol,
    unsigned short* __restrict__ w1f) {
  int idx = blockIdx.x * 256 + threadIdx.x;  // 0..65535
  int st = blockIdx.y;
  const float* w1 = st ? w1_fol : w1_pre;
  int j = idx & 7;
  int lane = (idx >> 3) & 63;
  int c = (idx >> 9) & 7;
  int kk = idx >> 12;
  int k = kk * 32 + ((lane >> 4) << 3) + j;
  int d = c * 16 + (lane & 15);
  __hip_bfloat16 hb = __float2bfloat16(w1[(size_t)k * AD_ + d]);
  w1f[(size_t)st * 65536 + idx] = *(unsigned short*)&hb;
}

// ---------------------------------------------------------------------------
// K1: inclusive prefix sum of is_valid -> pos (rank-1), per stream.
// ---------------------------------------------------------------------------
__global__ __launch_bounds__(1024) void k_scan(
    const int* __restrict__ valid_pre, const int* __restrict__ valid_fol,
    int* __restrict__ pos) {
  const int st = blockIdx.x;
  const int* valid = st ? valid_fol : valid_pre;
  __shared__ int buf[1024];
  const int t = threadIdx.x;
  buf[t] = valid[t];
  __syncthreads();
  for (int off = 1; off < 1024; off <<= 1) {
    int v = (t >= off) ? buf[t - off] : 0;
    __syncthreads();
    buf[t] += v;
    __syncthreads();
  }
  pos[st * N_ + t] = buf[t] - 1;
}

// ---------------------------------------------------------------------------
// K2: logits GEMM, CONTIGUOUS-BURST staging. 256 thr = 4 waves x 16 rows.
// Stage: each wave reads its 16 rows as one sequential 32KB stream (32 x 1KB
// float4 instrs, 8-deep batches), cvt->bf16, ds_write XOR-swizzled
// (byte ^= (row&7)<<4). Compute: per K-chunk one swizzled ds_read_b128 +
// 8 MFMA, B reloaded from L2-resident w1f. 64KB LDS -> 2 blocks/CU so
// block i+1's staging burst overlaps block i's compute. No K-loop barriers.
// ---------------------------------------------------------------------------
__global__ __launch_bounds__(256) void k_logits(
    const float* __restrict__ emb_pre, const float* __restrict__ emb_fol,
    const unsigned short* __restrict__ w1f,
    const float* __restrict__ w2_pre, const float* __restrict__ w2_fol,
    float* __restrict__ logits) {
  __shared__ __align__(16) unsigned char As[64 * 1024];   // 64 rows x 1KB bf16

  const int bid = blockIdx.x;
  const int st = bid >> 12;                  // 4096 blocks per stream
  const int m0 = (bid & 4095) * 64;
  const float* __restrict__ emb = st ? emb_fol : emb_pre;
  const float* __restrict__ w2  = st ? w2_fol : w2_pre;

  const int t = threadIdx.x;
  const int w = t >> 6, lane = t & 63;
  const int r16 = lane & 15, kq = lane >> 4;

  // ---- stage: wave w owns rows [w*16, w*16+16) = 32KB contiguous f32
  {
    const float* src = emb + (size_t)(m0 + w * 16) * H_;
#pragma unroll
    for (int bch = 0; bch < 4; ++bch) {
      float4 v[8];
#pragma unroll
      for (int i = 0; i < 8; ++i)
        v[i] = *(const float4*)(src + (size_t)(bch * 8 + i) * 256 + lane * 4);
#pragma unroll
      for (int i = 0; i < 8; ++i) {
        const int ii = bch * 8 + i;
        const int row = w * 16 + (ii >> 1);            // block-local row
        const int byte0 = (ii & 1) * 512 + lane * 8;   // byte within row
        const int byteS = byte0 ^ ((row & 7) << 4);    // XOR bank swizzle
        union { unsigned long long u; __hip_bfloat162 h[2]; } pk;
        pk.h[0] = __float22bfloat162_rn(make_float2(v[i].x, v[i].y));
        pk.h[1] = __float22bfloat162_rn(make_float2(v[i].z, v[i].w));
        *(unsigned long long*)&As[row * 1024 + byteS] = pk.u;
      }
    }
  }
  __syncthreads();

  // ---- compute: 16 K-chunks, no barriers
  const unsigned short* __restrict__ bb = w1f + (size_t)st * 65536 + (size_t)lane * 8;
  const int arow = w * 16 + r16;
  const int rsw = (r16 & 7) << 4;

  f32x4 acc[8];
#pragma unroll
  for (int cc = 0; cc < 8; ++cc) acc[cc] = (f32x4){0.f, 0.f, 0.f, 0.f};

  short8 B[8];
#pragma unroll
  for (int cc = 0; cc < 8; ++cc) B[cc] = *(const short8*)(bb + cc * 512);

#pragma unroll
  for (int kk = 0; kk < 16; ++kk) {
    const int byteS = (kk * 64 + kq * 16) ^ rsw;
    short8 a = *(const short8*)&As[arow * 1024 + byteS];
#pragma unroll
    for (int cc = 0; cc < 8; ++cc)
      acc[cc] = __builtin_amdgcn_mfma_f32_16x16x32_bf16(a, B[cc], acc[cc], 0, 0, 0);
    if (kk < 15) {
#pragma unroll
      for (int cc = 0; cc < 8; ++cc)
        B[cc] = *(const short8*)(bb + (kk + 1) * 4096 + cc * 512);
    }
  }

  // ---- epilogue: tanh (exp-form), @W2, 16-lane reduce, write logits
  float w2v0[8], w2v1[8];
#pragma unroll
  for (int cc = 0; cc < 8; ++cc) {
    w2v0[cc] = w2[(cc * 16 + r16) * 2 + 0];
    w2v1[cc] = w2[(cc * 16 + r16) * 2 + 1];
  }
#pragma unroll
  for (int q = 0; q < 4; ++q) {
    float p0 = 0.f, p1 = 0.f;
#pragma unroll
    for (int cc = 0; cc < 8; ++cc) {
      float xc = fminf(fmaxf(acc[cc][q], -10.f), 10.f);
      float e  = __expf(2.f * xc);
      float th = (e - 1.f) / (e + 1.f);
      p0 += th * w2v0[cc];
      p1 += th * w2v1[cc];
    }
    p0 += __shfl_xor(p0, 1); p0 += __shfl_xor(p0, 2);
    p0 += __shfl_xor(p0, 4); p0 += __shfl_xor(p0, 8);
    p1 += __shfl_xor(p1, 1); p1 += __shfl_xor(p1, 2);
    p1 += __shfl_xor(p1, 4); p1 += __shfl_xor(p1, 8);
    if (r16 == 0) {
      int m = m0 + w * 16 + kq * 4 + q;
      logits[((size_t)st * M_TOTAL + m) * 2 + 0] = p0;
      logits[((size_t)st * M_TOTAL + m) * 2 + 1] = p1;
    }
  }
}

// ---------------------------------------------------------------------------
// K3: per (stream, n): double softmax over s (source space), fold r-mean.
// logits layout [st][s][n][2]; wbar [st][n][s].
// ---------------------------------------------------------------------------
template <bool MAXRED>
__device__ __forceinline__ float blockRed(float v, float* buf) {
#pragma unroll
  for (int off = 32; off; off >>= 1) {
    float o = __shfl_xor(v, off);
    v = MAXRED ? fmaxf(v, o) : (v + o);
  }
  __syncthreads();
  if ((threadIdx.x & 63) == 0) buf[threadIdx.x >> 6] = v;
  __syncthreads();
  float r = buf[0];
#pragma unroll
  for (int i = 1; i < 4; ++i) r = MAXRED ? fmaxf(r, buf[i]) : (r + buf[i]);
  return r;
}

__global__ __launch_bounds__(256) void k_softmax(
    const float* __restrict__ logits,
    const unsigned char* __restrict__ mask_pre, const unsigned char* __restrict__ mask_fol,
    float* __restrict__ wbar) {
  const int n  = blockIdx.x;
  const int st = blockIdx.y;
  const unsigned char* mask = st ? mask_fol : mask_pre;
  const int s = threadIdx.x;

  float2 l = *(const float2*)&logits[((size_t)st * M_TOTAL + (size_t)s * N_ + n) * 2];
  const bool mk = mask[(size_t)n * S_ + s] != 0;

  __shared__ float buf[4];
  float q[2];
  float lv[2] = {l.x, l.y};
#pragma unroll
  for (int r = 0; r < 2; ++r) {
    float m1 = blockRed<true>(lv[r], buf);
    float e1 = __expf(lv[r] - m1);
    float s1 = blockRed<false>(e1, buf);
    float p1 = e1 / s1;                       // first softmax (unmasked)
    float v  = mk ? -INFINITY : p1;           // mask the probabilities
    float m2 = blockRed<true>(v, buf);
    float e2 = mk ? 0.f : __expf(v - m2);
    float s2 = blockRed<false>(e2, buf);
    q[r] = e2 / s2;                           // second softmax
  }
  wbar[((size_t)st * N_ + n) * S_ + s] = 0.5f * (q[0] + q[1]);
}

// ---------------------------------------------------------------------------
// K4: PV in memory order. Block = (st, n-chunk of 16, s-half). Per s-step one
// 32 KB contiguous burst (16 adjacent n-rows x full H). part[st][sh][n][h].
// ---------------------------------------------------------------------------
__global__ __launch_bounds__(512) void k_pv2(
    const float* __restrict__ emb_pre, const float* __restrict__ emb_fol,
    const float* __restrict__ wbar,
    float* __restrict__ part) {
  const int bid = blockIdx.x;          // 0..255
  const int st  = bid >> 7;
  const int idx = bid & 127;
  const int nc  = idx >> 1;            // 0..63
  const int sh  = idx & 1;             // 0..1
  const int n0 = nc * 16, s0 = sh * 128;
  const float* __restrict__ emb = st ? emb_fol : emb_pre;

  const int t = threadIdx.x;
  const int nl = t >> 5;               // 0..15 (n-row within chunk)
  const int c0 = (t & 31) * 4;         // h-base; acc j covers c0 + j*128

  __shared__ float wl[16][128];
  for (int i = t; i < 2048; i += 512) {
    int j = i >> 7, sl = i & 127;
    wl[j][sl] = wbar[((size_t)st * N_ + n0 + j) * S_ + s0 + sl];
  }
  __syncthreads();

  float4 acc[4], cur[4], nxt[4];
#pragma unroll
  for (int j = 0; j < 4; ++j) acc[j] = (float4){0.f, 0.f, 0.f, 0.f};

  // s descending (most recently L3-resident rows first)
  const float* rowp = emb + ((size_t)(s0 + 127) * N_ + n0 + nl) * H_ + c0;
  const size_t SSTR = (size_t)N_ * H_;
#pragma unroll
  for (int j = 0; j < 4; ++j) cur[j] = *(const float4*)(rowp + j * 128);

  for (int sl = 127; sl >= 0; --sl) {
    const float* nrow = rowp - SSTR;
    if (sl > 0) {
#pragma unroll
      for (int j = 0; j < 4; ++j) nxt[j] = *(const float4*)(nrow + j * 128);
    }
    const float wv = wl[nl][sl];
#pragma unroll
    for (int j = 0; j < 4; ++j) {
      acc[j].x += wv * cur[j].x;
      acc[j].y += wv * cur[j].y;
      acc[j].z += wv * cur[j].z;
      acc[j].w += wv * cur[j].w;
    }
#pragma unroll
    for (int j = 0; j < 4; ++j) cur[j] = nxt[j];
    rowp = nrow;
  }

  float* pp = part + (((size_t)(st * 2 + sh) * N_) + n0 + nl) * H_ + c0;
#pragma unroll
  for (int j = 0; j < 4; ++j) *(float4*)(pp + j * 128) = acc[j];
}

// ---------------------------------------------------------------------------
// K5: combine s-halves + valid/pos gather -> out[n][st*512 + h].
// ---------------------------------------------------------------------------
__global__ __launch_bounds__(256) void k_combine(
    const float* __restrict__ part, const int* __restrict__ pos,
    const int* __restrict__ valid_pre, const int* __restrict__ valid_fol,
    float* __restrict__ out) {
  const int n = blockIdx.x, t = threadIdx.x;
  const int st = t >> 7;
  const int c = (t & 127) * 4;
  const int* valid = st ? valid_fol : valid_pre;
  float4 r = {0.f, 0.f, 0.f, 0.f};
  if (valid[n] > 0) {
    int np = pos[st * N_ + n]; if (np < 0) np = 0;
    float4 a = *(const float4*)&part[(((size_t)(st * 2 + 0) * N_) + np) * H_ + c];
    float4 b = *(const float4*)&part[(((size_t)(st * 2 + 1) * N_) + np) * H_ + c];
    r.x = a.x + b.x; r.y = a.y + b.y; r.z = a.z + b.z; r.w = a.w + b.w;
  }
  *(float4*)&out[(size_t)n * 1024 + st * 512 + c] = r;
}

// ---------------------------------------------------------------------------
extern "C" void kernel_launch(void* const* d_in, const int* in_sizes, int n_in,
                              void* d_out, int out_size, void* d_ws, size_t ws_size,
                              hipStream_t stream) {
  const float* emb_pre = (const float*)d_in[0];
  const float* emb_fol = (const float*)d_in[1];
  const unsigned char* mask_pre = (const unsigned char*)d_in[2];
  const unsigned char* mask_fol = (const unsigned char*)d_in[3];
  const int* valid_pre = (const int*)d_in[4];
  const int* valid_fol = (const int*)d_in[5];
  const float* w1_pre = (const float*)d_in[6];
  const float* w2_pre = (const float*)d_in[7];
  const float* w1_fol = (const float*)d_in[8];
  const float* w2_fol = (const float*)d_in[9];
  float* out = (float*)d_out;

  char* ws = (char*)d_ws;
  unsigned short* w1f = (unsigned short*)ws;                    // 256 KiB
  int*   pos    = (int*)(ws + 262144);                          // 8 KiB
  float* logits = (float*)(ws + 270336);                        // 4 MiB  [2][S][N][2]
  float* wbar   = (float*)(ws + 270336 + 4194304);              // 2 MiB  [2][N][S]
  float* part   = (float*)(ws + 270336 + 4194304 + 2097152);    // 8 MiB  [2][2][N][H]

  hipLaunchKernelGGL(k_w1frag, dim3(256, 2), dim3(256), 0, stream,
                     w1_pre, w1_fol, w1f);
  hipLaunchKernelGGL(k_scan, dim3(2), dim3(1024), 0, stream,
                     valid_pre, valid_fol, pos);
  hipLaunchKernelGGL(k_logits, dim3(8192), dim3(256), 0, stream,
                     emb_pre, emb_fol, w1f, w2_pre, w2_fol, logits);
  hipLaunchKernelGGL(k_softmax, dim3(N_, 2), dim3(256), 0, stream,
                     logits, mask_pre, mask_fol, wbar);
  hipLaunchKernelGGL(k_pv2, dim3(256), dim3(512), 0, stream,
                     emb_pre, emb_fol, wbar, part);
  hipLaunchKernelGGL(k_combine, dim3(N_), dim3(256), 0, stream,
                     part, pos, valid_pre, valid_fol, out);
}